// Round 14
// baseline (98.500 us; speedup 1.0000x reference)
//
#include <hip/hip_runtime.h>
#include <hip/hip_fp16.h>

typedef unsigned int uint;

#define NH_   4096
#define NNODE 8192
#define NEDGE 262144
#define TS    4096
#define RT    17.4f
#define RIDX  (((float)(TS - 1)) / RT)

// ---- workspace layout (float offsets) ----
#define OFF_H      0        // 8192*28
#define OFF_SC1    229376   // 8192*16
#define OFF_SCALS  360448   // 32*10
#define OFF_MIDS   360768   // 32*16 (contiguous with SCALS: 832)
#define OFF_TABU   361280   // 4096*64 uints (bf16-packed r-table, scales folded)
#define OFF_SOFF   623424   // 8256 ints (CSR offsets by dst)
#define OFF_EC     631680   // 262144 uint4 (edge-order: dst, geo)
#define OFF_SA     1680256  // 262144 uint4 (dst-sorted: src, geo)

// ---- compile-time unroll ----
template <int I> struct ic { static constexpr int v = I; };
template <int N, typename F>
__device__ __forceinline__ void UN(F&& f) {
  if constexpr (N > 0) { UN<N - 1>(f); f(ic<N - 1>{}); }
}

template <int K>
__device__ __forceinline__ float f4c(float4 v) {
  if constexpr (K == 0) return v.x;
  else if constexpr (K == 1) return v.y;
  else if constexpr (K == 2) return v.z;
  else return v.w;
}
template <int C>
__device__ __forceinline__ float f4get(const float4* v) {
  return f4c<C & 3>(v[C >> 2]);
}
template <int K>
__device__ __forceinline__ uint u4c(uint4 v) {
  if constexpr (K == 0) return v.x;
  else if constexpr (K == 1) return v.y;
  else if constexpr (K == 2) return v.z;
  else return v.w;
}
// unpack bf16-pair channel CH from packed uint4 regs
template <int CH>
__device__ __forceinline__ float upk(const uint4* wr) {
  constexpr int pr = CH >> 1;
  uint u = u4c<pr & 3>(wr[pr >> 2]);
  if constexpr (CH & 1) return __uint_as_float(u & 0xffff0000u);
  else return __uint_as_float(u << 16);
}

__device__ __forceinline__ float sigmoidf_(float v) { return 1.0f / (1.0f + __expf(-v)); }

// full-wave compacting reduction: C channels -> channel (lane & (C-1))
template <int C, int B>
__device__ __forceinline__ void cred_rec(float* a, int lane) {
  if constexpr ((1 << B) < C) {
    const bool hi = (lane >> B) & 1;
    constexpr int n = C >> (B + 1);
    UN<n>([&](auto j){
      float s0 = a[2 * j.v], s1 = a[2 * j.v + 1];
      float send = hi ? s0 : s1;
      float recv = __shfl_xor(send, 1 << B);
      a[j.v] = (hi ? s1 : s0) + recv;
    });
    cred_rec<C, B + 1>(a, lane);
  }
}
template <int C>
__device__ __forceinline__ float creduce(float* v, int lane) {
  cred_rec<C, 0>(v, lane);
  float s = v[0];
#pragma unroll
  for (int m = C; m < 64; m <<= 1) s += __shfl_xor(s, m);
  return s;
}
// half-wave (32-lane) compacting reduction of 64 channels, 5 steps.
// After: a[0] = ch (lane&31), a[1] = ch 32+(lane&31), summed over the half.
template <int B>
__device__ __forceinline__ void cred32_rec(float* a, int lane) {
  if constexpr (B < 5) {
    const bool hi = (lane >> B) & 1;
    constexpr int n = 64 >> (B + 1);
    UN<n>([&](auto j){
      float s0 = a[2 * j.v], s1 = a[2 * j.v + 1];
      float send = hi ? s0 : s1;
      float recv = __shfl_xor(send, 1 << B);
      a[j.v] = (hi ? s1 : s0) + recv;
    });
    cred32_rec<B + 1>(a, lane);
  }
}

__device__ __forceinline__ void make_emb(float r, float* embs) {
  float rb = r * 0.45f;
  UN<10>([&](auto b){ float d = rb - (float)b.v; embs[b.v] = __expf(-d * d); });
}

// sh from pre-normalized direction
__device__ __forceinline__ void make_sh_n(float x, float y, float z, float* sh) {
  float x2 = x * x, y2 = y * y, z2 = z * z;
  float shA = 3.87298334620742f * x * z;
  float shB = 1.93649167310371f * (z2 - x2);
  sh[0] = 1.f;
  sh[1] = 1.73205080756888f * x;
  sh[2] = 1.73205080756888f * y;
  sh[3] = 1.73205080756888f * z;
  sh[4] = shA;
  sh[5] = 3.87298334620742f * x * y;
  sh[6] = 2.23606797749979f * (y2 - 0.5f * (x2 + z2));
  sh[7] = 3.87298334620742f * y * z;
  sh[8] = shB;
  sh[9]  = 1.08012344973464f * (shA * z + shB * x);
  sh[10] = 2.64575131106459f * shA * y;
  sh[11] = 1.62018517460197f * (4.f * y2 - x2 - z2) * x;
  sh[12] = 1.32287565553230f * y * (2.f * y2 - 3.f * x2 - 3.f * z2);
  sh[13] = 1.62018517460197f * z * (4.f * y2 - x2 - z2);
  sh[14] = 2.64575131106459f * shB * y;
  sh[15] = 1.08012344973464f * (shB * z - shA * x);
}

// ---------------------------------------------------------------------------
// k_prep (512-thread blocks, block-ranged) — unchanged from r13.
// ---------------------------------------------------------------------------
__global__ void __launch_bounds__(512, 2) k_prep(
    const float* __restrict__ wt_pos, const float* __restrict__ mt_pos,
    const float* __restrict__ wt_x, const float* __restrict__ mt_x,
    const float* __restrict__ lin1a, const float* __restrict__ sc1w,
    const float* __restrict__ fc1w1, const float* __restrict__ fc1w2,
    const float* __restrict__ fc2w1, const float* __restrict__ fc2w2,
    const int* __restrict__ edst,
    float* __restrict__ h, float* __restrict__ sc1,
    uint* __restrict__ tabU, float* __restrict__ zacc,
    uint4* __restrict__ edgeC, uint4* __restrict__ sortedA,
    int* __restrict__ soff)
{
  __shared__ float smemf[1024];
  const int blk = blockIdx.x;
  const int tid = threadIdx.x;

  if (blk < 1024) {
    // ---- r-table: 4 samples/block, 8 waves (2 per sample) ----
    float (*sv)[2][128] = (float(*)[2][128])smemf;
    const int lane = tid & 63;
    const int wv = tid >> 6;
    const int si = wv >> 1;           // sample 0..3
    const int role = wv & 1;
    const int s = blk * 4 + si;
    const float r = (float)s * (RT / (float)(TS - 1));
    float emb[10];
    make_emb(r, emb);
    const float FS1 = 0.003125f;
    const float FS2 = 0.015625f;

    const float* wmat = (role == 0) ? fc1w1 : fc2w1;
    UN<2>([&](auto hh){
      int kk = lane + hh.v * 64;
      float hk = 0.f;
      UN<10>([&](auto j){ hk = fmaf(emb[j.v], wmat[j.v * 128 + kk], hk); });
      sv[si][role][kk] = hk * sigmoidf_(hk);
    });
    __syncthreads();

    float acc = 0.f;
    if (role == 0) {
      const float* base = fc1w2 + lane;
#pragma unroll 4
      for (int k = 0; k < 128; ++k)
        acc = fmaf(sv[si][0][k], base[k * 100], acc);
      acc *= FS1;
    } else {
      const bool isW1 = lane < 36;
      const bool isW2 = (lane >= 36) && (lane < 52);
      if (isW1 || isW2) {
        const float* base = isW1 ? (fc1w2 + 64 + lane) : (fc2w2 + (lane - 36));
        const int stride = isW1 ? 100 : 16;
        const int svi = isW1 ? 0 : 1;
#pragma unroll 4
        for (int k = 0; k < 128; ++k)
          acc = fmaf(sv[si][svi][k], base[k * stride], acc);
        acc *= (isW1 ? FS1 : FS2);
      }
    }

    int srcLo = 0, srcHi = 0;
    bool valid = false;
    if (role == 0) {
      srcLo = 2 * lane; srcHi = srcLo + 1; valid = lane < 32;
    } else {
      if (lane >= 32 && lane < 50)      { int i = lane - 32; srcLo = 2 * i;      srcHi = 2 * i + 1;  valid = true; }
      else if (lane >= 52 && lane < 60) { int i = lane - 52; srcLo = 36 + 2 * i; srcHi = 37 + 2 * i; valid = true; }
    }
    float lo = __shfl(acc, srcLo);
    float hi = __shfl(acc, srcHi);
    if (valid) {
      uint u = ((__float_as_uint(lo) + 0x8000u) >> 16)
             | (((__float_as_uint(hi) + 0x8000u) >> 16) << 16);
      tabU[(size_t)s * 64 + lane] = u;
    }
  } else if (blk < 1040) {
    // ---- node1 ----
    int i = (blk - 1024) * 512 + tid;
    const float* xp = (i < NH_) ? (wt_x + i * 25) : (mt_x + (i - NH_) * 25);
    float xr[25];
    UN<25>([&](auto m){ xr[m.v] = xp[m.v]; });
    float ah[25], as[16];
    UN<25>([&](auto j){ ah[j.v] = 0.f; });
    UN<16>([&](auto j){ as[j.v] = 0.f; });
    UN<25>([&](auto m){
      float xm = xr[m.v];
      UN<25>([&](auto j){ ah[j.v] = fmaf(xm, lin1a[m.v * 25 + j.v], ah[j.v]); });
      UN<16>([&](auto j){ as[j.v] = fmaf(xm, sc1w[m.v * 16 + j.v], as[j.v]); });
    });
    UN<25>([&](auto j){ h[i * 28 + j.v] = 0.2f * ah[j.v]; });
    UN<16>([&](auto j){ sc1[i * 16 + j.v] = 0.2f * as[j.v]; });
  } else if (blk < 1104) {
    // ---- sort + geometry: one block per group (4096 edges, 8/thread) ----
    int* hist = (int*)smemf;
    int* cnt  = hist + 128;
    const int g = blk - 1040;
    if (tid < 128) hist[tid] = 0;
    __syncthreads();
    int dl[8]; uint gy[8], gz[8];
    UN<8>([&](auto k){
      const int e = g * 4096 + k.v * 512 + tid;
      const int src = e >> 5;
      const int dst = edst[e];
      dl[k.v] = dst & 127;
      atomicAdd(&hist[dl[k.v]], 1);
      const float* ps = (src < NH_) ? (wt_pos + src * 3) : (mt_pos + (src - NH_) * 3);
      const float* pd = (dst < NH_) ? (wt_pos + dst * 3) : (mt_pos + (dst - NH_) * 3);
      float vx = ps[0] - pd[0], vy = ps[1] - pd[1], vz = ps[2] - pd[2];
      float r = sqrtf(vx * vx + vy * vy + vz * vz);
      int ti = min((int)(r * RIDX + 0.5f), TS - 1);
      float rinv = 1.0f / fmaxf(r, 1e-9f);
      uint hx = (uint)__half_as_ushort(__float2half(vx * rinv));
      uint hy = (uint)__half_as_ushort(__float2half(vy * rinv));
      uint hz = (uint)__half_as_ushort(__float2half(vz * rinv));
      gy[k.v] = hx | (hy << 16);
      gz[k.v] = hz | ((uint)ti << 16);
      edgeC[e] = make_uint4((uint)dst, gy[k.v], gz[k.v], 0u);
    });
    __syncthreads();
    if (tid < 64) {
      int s0 = hist[2 * tid], s1 = hist[2 * tid + 1];
      int ps = s0 + s1;
      int sum = ps;
#pragma unroll
      for (int m = 1; m < 64; m <<= 1) {
        int t = __shfl_up(sum, m);
        if (tid >= m) sum += t;
      }
      int excl = sum - ps;
      cnt[2 * tid] = excl;
      cnt[2 * tid + 1] = excl + s0;
      soff[g * 128 + 2 * tid] = g * 4096 + excl;
      soff[g * 128 + 2 * tid + 1] = g * 4096 + excl + s0;
    }
    if (g == 0 && tid == 511) soff[NNODE] = NEDGE;
    __syncthreads();
    UN<8>([&](auto k){
      const int e = g * 4096 + k.v * 512 + tid;
      int slot = atomicAdd(&cnt[dl[k.v]], 1);
      sortedA[g * 4096 + slot] = make_uint4((uint)(e >> 5), gy[k.v], gz[k.v], 0u);
    });
  } else {
    for (int z = tid; z < 832; z += 512) zacc[z] = 0.f;
  }
}

// ---------------------------------------------------------------------------
// k_mega: block = 4 nodes [blk*4, blk*4+4), 128 threads (2 waves), grid 2048.
//   Phase A: HALF-wave per dst (avg in-degree = 32 -> full lanes); geo from
//     sortedA (depth-2 chain) + software prefetch of next iteration's gg;
//     42-ch half-wave tree reduce -> Atile LDS.
//   Phase B: node2 (4 threads) -> nodeHs LDS + scal group atomics.
//   Phase C: 128 src-major edges (all threads), geo from edgeC;
//     creduce -> midsum atomics.
// bounds (128,3): VGPR cap ~170 — the proven no-spill point (r12: cap 128
// spilled this body; r11/r13: cap 170 -> 84 VGPR, zero spill).
// ---------------------------------------------------------------------------
__global__ void __launch_bounds__(128, 3) k_mega(
    const int* __restrict__ soff, const uint4* __restrict__ sortedA,
    const uint4* __restrict__ edgeC,
    const uint* __restrict__ tabU, const float* __restrict__ h,
    const float* __restrict__ sc1,
    const float* __restrict__ l2a0, const float* __restrict__ l2a1,
    const float* __restrict__ l2a2, const float* __restrict__ l2a3,
    const float* __restrict__ l1b0, const float* __restrict__ l1b1,
    const float* __restrict__ l1b2, const float* __restrict__ l1b3,
    float* __restrict__ scalsum, float* __restrict__ midsum)
{
  __shared__ float Atile[4][44];
  __shared__ float nodeHs[4][36];

  const int tid = threadIdx.x;
  const int lane = tid & 63;
  const int li = lane & 31;
  const int hw = tid >> 5;                       // half-wave id 0..3
  const int dst = blockIdx.x * 4 + hw;

  // ---- Phase A: gather + accumulate + half-wave tree reduce ----
  {
    const int start = soff[dst];
    const int n = soff[dst + 1] - start;

    float acc[42];
    UN<42>([&](auto c){ acc[c.v] = 0.f; });

    const int nmax = max(n, __shfl_xor(n, 32));

    uint4 gg = make_uint4(0u, 0u, 0u, 0u);
    if (li < n) gg = sortedA[start + li];

#pragma unroll 1
    for (int it = 0; it < nmax; it += 32) {
      const int i = it + li;
      // prefetch next iteration's geo record
      uint4 ggn = gg;
      if (i + 32 < n) ggn = sortedA[start + i + 32];
      if (i < n) {
        const int src = (int)gg.x;
        float x = __half2float(__ushort_as_half((unsigned short)(gg.y & 0xffffu)));
        float y = __half2float(__ushort_as_half((unsigned short)(gg.y >> 16)));
        float z = __half2float(__ushort_as_half((unsigned short)(gg.z & 0xffffu)));
        const int ti = (int)(gg.z >> 16);
        const uint4* w4 = (const uint4*)(tabU + (size_t)ti * 64);
        uint4 wr[13];
        UN<13>([&](auto j){ wr[j.v] = w4[j.v]; });
        const float4* hp = (const float4*)(h + src * 28);
        float4 hq[7];
        UN<7>([&](auto j){ hq[j.v] = hp[j.v]; });
        float sh[16];
        make_sh_n(x, y, z, sh);

        UN<25>([&](auto mm){
          float t = f4get<mm.v>(hq) * upk<mm.v>(wr);
          UN<16>([&](auto v){ acc[v.v] = fmaf(t, l2a0[mm.v * 16 + v.v], acc[v.v]); });
        });
        {
          float p1[3] = {0.f, 0.f, 0.f};
          UN<25>([&](auto mm){
            float t = f4get<mm.v>(hq) * upk<25 + mm.v>(wr);
            UN<3>([&](auto v){ p1[v.v] = fmaf(t, l2a1[mm.v * 3 + v.v], p1[v.v]); });
          });
          UN<3>([&](auto v){
            UN<3>([&](auto m){ acc[16 + v.v * 3 + m.v] = fmaf(p1[v.v], sh[1 + m.v], acc[16 + v.v * 3 + m.v]); });
          });
        }
        {
          float p2[2] = {0.f, 0.f};
          UN<25>([&](auto mm){
            float t = f4get<mm.v>(hq) * upk<50 + mm.v>(wr);
            UN<2>([&](auto v){ p2[v.v] = fmaf(t, l2a2[mm.v * 2 + v.v], p2[v.v]); });
          });
          UN<2>([&](auto v){
            UN<5>([&](auto m){ acc[25 + v.v * 5 + m.v] = fmaf(p2[v.v], sh[4 + m.v], acc[25 + v.v * 5 + m.v]); });
          });
        }
        {
          float p3 = 0.f;
          UN<25>([&](auto mm){
            float t = f4get<mm.v>(hq) * upk<75 + mm.v>(wr);
            p3 = fmaf(t, l2a3[mm.v], p3);
          });
          UN<7>([&](auto m){ acc[35 + m.v] = fmaf(p3, sh[9 + m.v], acc[35 + m.v]); });
        }
      }
      gg = ggn;
    }

    float red[64];
    UN<42>([&](auto c){ red[c.v] = acc[c.v]; });
    UN<22>([&](auto c){ red[42 + c.v] = 0.f; });
    cred32_rec<0>(red, lane);
    Atile[hw][li] = red[0];
    if (li < 10) Atile[hw][32 + li] = red[1];
  }
  __syncthreads();

  // ---- Phase B: node2 for the block's 4 nodes ----
  if (tid < 4) {
    const int i = blockIdx.x * 4 + tid;
    float Ai[42];
    UN<42>([&](auto c){ Ai[c.v] = Atile[tid][c.v]; });
    const float CS_ = 0.38268343236509f, CX_ = 0.92387953251129f;
    float scal[10], gate[6];
    UN<10>([&](auto c){
      float s = CS_ * sc1[i * 16 + c.v] + CX_ * Ai[c.v];
      scal[c.v] = s * sigmoidf_(s);
    });
    UN<6>([&](auto c){
      float s = CS_ * sc1[i * 16 + 10 + c.v] + CX_ * Ai[10 + c.v];
      gate[c.v] = sigmoidf_(s);
    });
    UN<10>([&](auto v){
      float a = 0.f;
      UN<10>([&](auto u){ a = fmaf(scal[u.v], l1b0[u.v * 10 + v.v], a); });
      nodeHs[tid][v.v] = a * 0.31622776601684f;
    });
    UN<3>([&](auto v){
      UN<3>([&](auto m){
        float a = 0.f;
        UN<3>([&](auto u){ a = fmaf(Ai[16 + u.v * 3 + m.v] * gate[u.v], l1b1[u.v * 3 + v.v], a); });
        nodeHs[tid][10 + v.v * 3 + m.v] = a * 0.57735026918963f;
      });
    });
    UN<2>([&](auto v){
      UN<5>([&](auto m){
        float a = 0.f;
        UN<2>([&](auto u){ a = fmaf(Ai[25 + u.v * 5 + m.v] * gate[3 + u.v], l1b2[u.v * 2 + v.v], a); });
        nodeHs[tid][19 + v.v * 5 + m.v] = a * 0.70710678118655f;
      });
    });
    float b3 = l1b3[0];
    UN<7>([&](auto m){ nodeHs[tid][29 + m.v] = Ai[35 + m.v] * gate[5] * b3; });

    const int g = (i >> 7) & 31;
    UN<10>([&](auto c){ atomicAdd(&scalsum[g * 10 + c.v], scal[c.v]); });
  }
  __syncthreads();

  // ---- Phase C: edge2 for edges e in [blk*128, blk*128+128) ----
  {
    const int e = blockIdx.x * 128 + tid;
    const int sl = tid >> 5;                    // local src index 0..3
    uint4 gg = edgeC[e];
    const int dst2 = (int)gg.x;
    float x = __half2float(__ushort_as_half((unsigned short)(gg.y & 0xffffu)));
    float y = __half2float(__ushort_as_half((unsigned short)(gg.y >> 16)));
    float z = __half2float(__ushort_as_half((unsigned short)(gg.z & 0xffffu)));
    const int ti = (int)(gg.z >> 16);
    const uint4* w4 = (const uint4*)(tabU + (size_t)ti * 64 + 52);
    uint4 wr[2];
    wr[0] = w4[0]; wr[1] = w4[1];
    float acc[16];
    UN<16>([&](auto c){ acc[c.v] = upk<c.v>(wr); });

    float sh[16];
    make_sh_n(x, y, z, sh);

    const float* Hs = nodeHs[sl];
    float ev[16];
    UN<10>([&](auto c){ ev[c.v] = Hs[c.v] * acc[c.v]; });
    UN<3>([&](auto u){
      float d = 0.f;
      UN<3>([&](auto m){ d = fmaf(Hs[10 + u.v * 3 + m.v], sh[1 + m.v], d); });
      ev[10 + u.v] = d * 0.57735026918963f * acc[10 + u.v];
    });
    UN<2>([&](auto u){
      float d = 0.f;
      UN<5>([&](auto m){ d = fmaf(Hs[19 + u.v * 5 + m.v], sh[4 + m.v], d); });
      ev[13 + u.v] = d * 0.44721359549996f * acc[13 + u.v];
    });
    {
      float d = 0.f;
      UN<7>([&](auto m){ d = fmaf(Hs[29 + m.v], sh[9 + m.v], d); });
      ev[15] = d * 0.37796447300923f * acc[15];
    }

    const int g = (dst2 >> 7) & 31;
    float s = creduce<16>(ev, lane);
    if (lane < 16) atomicAdd(&midsum[g * 16 + lane], s);
  }
}

// finale: fold head through sc2_w / lin2b, one block
__global__ void k_final(const float* __restrict__ sc2w, const float* __restrict__ lin2b,
                        const float* __restrict__ headw, const float* __restrict__ headb,
                        const float* __restrict__ scalsum, const float* __restrict__ midsum,
                        float* __restrict__ out)
{
  __shared__ float WA[20];
  __shared__ float WB[32];
  int t = threadIdx.x;
  if (t < 20) {
    int j = t >> 1, o = t & 1;
    float a = 0.f;
    for (int c = 0; c < 256; ++c) a += sc2w[j * 256 + c] * headw[c * 2 + o];
    WA[t] = a;
  } else if (t < 52) {
    int q = t - 20, j = q >> 1, o = q & 1;
    float a = 0.f;
    for (int c = 0; c < 256; ++c) a += lin2b[j * 256 + c] * headw[c * 2 + o];
    WB[q] = a;
  }
  __syncthreads();
  if (t < 64) {
    int g = t & 31, o = t >> 5;
    float a = 0.f;
    for (int j = 0; j < 10; ++j) a += scalsum[g * 10 + j] * WA[j * 2 + o];
    float b = 0.f;
    for (int j = 0; j < 16; ++j) b += midsum[g * 16 + j] * WB[j * 2 + o];
    float y = a * (0.38268343236509f * 0.31622776601684f)
            + b * (0.92387953251129f * 0.25f);
    out[o * 32 + g] = y * (1.0f / 256.0f) + headb[o];
  }
}

extern "C" void kernel_launch(void* const* d_in, const int* in_sizes, int n_in,
                              void* d_out, int out_size, void* d_ws, size_t ws_size,
                              hipStream_t stream)
{
  float* ws = (float*)d_ws;
  const float* wt_pos = (const float*)d_in[0];
  const float* mt_pos = (const float*)d_in[1];
  const float* wt_x   = (const float*)d_in[2];
  const float* mt_x   = (const float*)d_in[3];
  const int* edst     = (const int*)d_in[7];
  const float* sc1w   = (const float*)d_in[8];
  const float* lin1a  = (const float*)d_in[9];
  const float* fc1w1  = (const float*)d_in[10];
  const float* fc1w2  = (const float*)d_in[11];
  const float* l2a0   = (const float*)d_in[12];
  const float* l2a1   = (const float*)d_in[13];
  const float* l2a2   = (const float*)d_in[14];
  const float* l2a3   = (const float*)d_in[15];
  const float* sc2w   = (const float*)d_in[16];
  const float* l1b0   = (const float*)d_in[17];
  const float* l1b1   = (const float*)d_in[18];
  const float* l1b2   = (const float*)d_in[19];
  const float* l1b3   = (const float*)d_in[20];
  const float* fc2w1  = (const float*)d_in[21];
  const float* fc2w2  = (const float*)d_in[22];
  const float* lin2b  = (const float*)d_in[23];
  const float* headw  = (const float*)d_in[24];
  const float* headb  = (const float*)d_in[25];

  float* h       = ws + OFF_H;
  float* sc1     = ws + OFF_SC1;
  float* scalsum = ws + OFF_SCALS;
  float* midsum  = ws + OFF_MIDS;
  uint*  tabU    = (uint*)(ws + OFF_TABU);
  int*   soff    = (int*)(ws + OFF_SOFF);
  uint4* edgeC   = (uint4*)(ws + OFF_EC);
  uint4* sortedA = (uint4*)(ws + OFF_SA);

  k_prep<<<1105, 512, 0, stream>>>(wt_pos, mt_pos, wt_x, mt_x, lin1a, sc1w,
                                   fc1w1, fc1w2, fc2w1, fc2w2, edst,
                                   h, sc1, tabU, scalsum, edgeC, sortedA, soff);
  k_mega<<<2048, 128, 0, stream>>>(soff, sortedA, edgeC, tabU, h, sc1,
                                   l2a0, l2a1, l2a2, l2a3,
                                   l1b0, l1b1, l1b2, l1b3,
                                   scalsum, midsum);
  k_final<<<1, 256, 0, stream>>>(sc2w, lin2b, headw, headb, scalsum, midsum, (float*)d_out);
}

// Round 15
// 65.481 us; speedup vs baseline: 1.5043x; 1.5043x over previous
//
#include <hip/hip_runtime.h>
#include <hip/hip_fp16.h>

typedef unsigned int uint;

#define NH_   4096
#define NNODE 8192
#define NEDGE 262144
#define TS    4096
#define RT    17.4f
#define RIDX  (((float)(TS - 1)) / RT)

// ---- workspace layout (float offsets) ----
#define OFF_H      0        // 8192*28
#define OFF_SC1    229376   // 8192*16
#define OFF_PART   360448   // 1024 blocks * 32 floats (scal[10] @0, mid[16] @16)
#define OFF_TABU   393216   // 4096*64 uints (bf16-packed r-table, scales folded)
#define OFF_SOFF   655360   // 8256 ints (CSR offsets by dst)
#define OFF_EC     663616   // 262144 uint4 (edge-order: dst, geo)
#define OFF_SA     1712192  // 262144 uint4 (dst-sorted: src, geo)

// ---- compile-time unroll ----
template <int I> struct ic { static constexpr int v = I; };
template <int N, typename F>
__device__ __forceinline__ void UN(F&& f) {
  if constexpr (N > 0) { UN<N - 1>(f); f(ic<N - 1>{}); }
}

template <int K>
__device__ __forceinline__ float f4c(float4 v) {
  if constexpr (K == 0) return v.x;
  else if constexpr (K == 1) return v.y;
  else if constexpr (K == 2) return v.z;
  else return v.w;
}
template <int C>
__device__ __forceinline__ float f4get(const float4* v) {
  return f4c<C & 3>(v[C >> 2]);
}
template <int K>
__device__ __forceinline__ uint u4c(uint4 v) {
  if constexpr (K == 0) return v.x;
  else if constexpr (K == 1) return v.y;
  else if constexpr (K == 2) return v.z;
  else return v.w;
}
// unpack bf16-pair channel CH from packed uint4 regs
template <int CH>
__device__ __forceinline__ float upk(const uint4* wr) {
  constexpr int pr = CH >> 1;
  uint u = u4c<pr & 3>(wr[pr >> 2]);
  if constexpr (CH & 1) return __uint_as_float(u & 0xffff0000u);
  else return __uint_as_float(u << 16);
}

__device__ __forceinline__ float sigmoidf_(float v) { return 1.0f / (1.0f + __expf(-v)); }

// full-wave compacting reduction: C channels -> channel (lane & (C-1))
template <int C, int B>
__device__ __forceinline__ void cred_rec(float* a, int lane) {
  if constexpr ((1 << B) < C) {
    const bool hi = (lane >> B) & 1;
    constexpr int n = C >> (B + 1);
    UN<n>([&](auto j){
      float s0 = a[2 * j.v], s1 = a[2 * j.v + 1];
      float send = hi ? s0 : s1;
      float recv = __shfl_xor(send, 1 << B);
      a[j.v] = (hi ? s1 : s0) + recv;
    });
    cred_rec<C, B + 1>(a, lane);
  }
}
template <int C>
__device__ __forceinline__ float creduce(float* v, int lane) {
  cred_rec<C, 0>(v, lane);
  float s = v[0];
#pragma unroll
  for (int m = C; m < 64; m <<= 1) s += __shfl_xor(s, m);
  return s;
}
// half-wave (32-lane) compacting reduction of 64 channels, 5 steps.
template <int B>
__device__ __forceinline__ void cred32_rec(float* a, int lane) {
  if constexpr (B < 5) {
    const bool hi = (lane >> B) & 1;
    constexpr int n = 64 >> (B + 1);
    UN<n>([&](auto j){
      float s0 = a[2 * j.v], s1 = a[2 * j.v + 1];
      float send = hi ? s0 : s1;
      float recv = __shfl_xor(send, 1 << B);
      a[j.v] = (hi ? s1 : s0) + recv;
    });
    cred32_rec<B + 1>(a, lane);
  }
}

__device__ __forceinline__ void make_emb(float r, float* embs) {
  float rb = r * 0.45f;
  UN<10>([&](auto b){ float d = rb - (float)b.v; embs[b.v] = __expf(-d * d); });
}

// sh from pre-normalized direction
__device__ __forceinline__ void make_sh_n(float x, float y, float z, float* sh) {
  float x2 = x * x, y2 = y * y, z2 = z * z;
  float shA = 3.87298334620742f * x * z;
  float shB = 1.93649167310371f * (z2 - x2);
  sh[0] = 1.f;
  sh[1] = 1.73205080756888f * x;
  sh[2] = 1.73205080756888f * y;
  sh[3] = 1.73205080756888f * z;
  sh[4] = shA;
  sh[5] = 3.87298334620742f * x * y;
  sh[6] = 2.23606797749979f * (y2 - 0.5f * (x2 + z2));
  sh[7] = 3.87298334620742f * y * z;
  sh[8] = shB;
  sh[9]  = 1.08012344973464f * (shA * z + shB * x);
  sh[10] = 2.64575131106459f * shA * y;
  sh[11] = 1.62018517460197f * (4.f * y2 - x2 - z2) * x;
  sh[12] = 1.32287565553230f * y * (2.f * y2 - 3.f * x2 - 3.f * z2);
  sh[13] = 1.62018517460197f * z * (4.f * y2 - x2 - z2);
  sh[14] = 2.64575131106459f * shB * y;
  sh[15] = 1.08012344973464f * (shB * z - shA * x);
}

// ---------------------------------------------------------------------------
// k_prep (512-thread blocks, block-ranged): table / node1 / sort+geo.
// (zero-init block removed — no global accumulators remain.)
// ---------------------------------------------------------------------------
__global__ void __launch_bounds__(512, 2) k_prep(
    const float* __restrict__ wt_pos, const float* __restrict__ mt_pos,
    const float* __restrict__ wt_x, const float* __restrict__ mt_x,
    const float* __restrict__ lin1a, const float* __restrict__ sc1w,
    const float* __restrict__ fc1w1, const float* __restrict__ fc1w2,
    const float* __restrict__ fc2w1, const float* __restrict__ fc2w2,
    const int* __restrict__ edst,
    float* __restrict__ h, float* __restrict__ sc1,
    uint* __restrict__ tabU,
    uint4* __restrict__ edgeC, uint4* __restrict__ sortedA,
    int* __restrict__ soff)
{
  __shared__ float smemf[1024];
  const int blk = blockIdx.x;
  const int tid = threadIdx.x;

  if (blk < 1024) {
    // ---- r-table: 4 samples/block, 8 waves (2 per sample) ----
    float (*sv)[2][128] = (float(*)[2][128])smemf;
    const int lane = tid & 63;
    const int wv = tid >> 6;
    const int si = wv >> 1;           // sample 0..3
    const int role = wv & 1;
    const int s = blk * 4 + si;
    const float r = (float)s * (RT / (float)(TS - 1));
    float emb[10];
    make_emb(r, emb);
    const float FS1 = 0.003125f;
    const float FS2 = 0.015625f;

    const float* wmat = (role == 0) ? fc1w1 : fc2w1;
    UN<2>([&](auto hh){
      int kk = lane + hh.v * 64;
      float hk = 0.f;
      UN<10>([&](auto j){ hk = fmaf(emb[j.v], wmat[j.v * 128 + kk], hk); });
      sv[si][role][kk] = hk * sigmoidf_(hk);
    });
    __syncthreads();

    float acc = 0.f;
    if (role == 0) {
      const float* base = fc1w2 + lane;
#pragma unroll 4
      for (int k = 0; k < 128; ++k)
        acc = fmaf(sv[si][0][k], base[k * 100], acc);
      acc *= FS1;
    } else {
      const bool isW1 = lane < 36;
      const bool isW2 = (lane >= 36) && (lane < 52);
      if (isW1 || isW2) {
        const float* base = isW1 ? (fc1w2 + 64 + lane) : (fc2w2 + (lane - 36));
        const int stride = isW1 ? 100 : 16;
        const int svi = isW1 ? 0 : 1;
#pragma unroll 4
        for (int k = 0; k < 128; ++k)
          acc = fmaf(sv[si][svi][k], base[k * stride], acc);
        acc *= (isW1 ? FS1 : FS2);
      }
    }

    int srcLo = 0, srcHi = 0;
    bool valid = false;
    if (role == 0) {
      srcLo = 2 * lane; srcHi = srcLo + 1; valid = lane < 32;
    } else {
      if (lane >= 32 && lane < 50)      { int i = lane - 32; srcLo = 2 * i;      srcHi = 2 * i + 1;  valid = true; }
      else if (lane >= 52 && lane < 60) { int i = lane - 52; srcLo = 36 + 2 * i; srcHi = 37 + 2 * i; valid = true; }
    }
    float lo = __shfl(acc, srcLo);
    float hi = __shfl(acc, srcHi);
    if (valid) {
      uint u = ((__float_as_uint(lo) + 0x8000u) >> 16)
             | (((__float_as_uint(hi) + 0x8000u) >> 16) << 16);
      tabU[(size_t)s * 64 + lane] = u;
    }
  } else if (blk < 1040) {
    // ---- node1 ----
    int i = (blk - 1024) * 512 + tid;
    const float* xp = (i < NH_) ? (wt_x + i * 25) : (mt_x + (i - NH_) * 25);
    float xr[25];
    UN<25>([&](auto m){ xr[m.v] = xp[m.v]; });
    float ah[25], as[16];
    UN<25>([&](auto j){ ah[j.v] = 0.f; });
    UN<16>([&](auto j){ as[j.v] = 0.f; });
    UN<25>([&](auto m){
      float xm = xr[m.v];
      UN<25>([&](auto j){ ah[j.v] = fmaf(xm, lin1a[m.v * 25 + j.v], ah[j.v]); });
      UN<16>([&](auto j){ as[j.v] = fmaf(xm, sc1w[m.v * 16 + j.v], as[j.v]); });
    });
    UN<25>([&](auto j){ h[i * 28 + j.v] = 0.2f * ah[j.v]; });
    UN<16>([&](auto j){ sc1[i * 16 + j.v] = 0.2f * as[j.v]; });
  } else {
    // ---- sort + geometry: one block per group (4096 edges, 8/thread) ----
    int* hist = (int*)smemf;
    int* cnt  = hist + 128;
    const int g = blk - 1040;
    if (tid < 128) hist[tid] = 0;
    __syncthreads();
    int dl[8]; uint gy[8], gz[8];
    UN<8>([&](auto k){
      const int e = g * 4096 + k.v * 512 + tid;
      const int src = e >> 5;
      const int dst = edst[e];
      dl[k.v] = dst & 127;
      atomicAdd(&hist[dl[k.v]], 1);
      const float* ps = (src < NH_) ? (wt_pos + src * 3) : (mt_pos + (src - NH_) * 3);
      const float* pd = (dst < NH_) ? (wt_pos + dst * 3) : (mt_pos + (dst - NH_) * 3);
      float vx = ps[0] - pd[0], vy = ps[1] - pd[1], vz = ps[2] - pd[2];
      float r = sqrtf(vx * vx + vy * vy + vz * vz);
      int ti = min((int)(r * RIDX + 0.5f), TS - 1);
      float rinv = 1.0f / fmaxf(r, 1e-9f);
      uint hx = (uint)__half_as_ushort(__float2half(vx * rinv));
      uint hy = (uint)__half_as_ushort(__float2half(vy * rinv));
      uint hz = (uint)__half_as_ushort(__float2half(vz * rinv));
      gy[k.v] = hx | (hy << 16);
      gz[k.v] = hz | ((uint)ti << 16);
      edgeC[e] = make_uint4((uint)dst, gy[k.v], gz[k.v], 0u);
    });
    __syncthreads();
    if (tid < 64) {
      int s0 = hist[2 * tid], s1 = hist[2 * tid + 1];
      int ps = s0 + s1;
      int sum = ps;
#pragma unroll
      for (int m = 1; m < 64; m <<= 1) {
        int t = __shfl_up(sum, m);
        if (tid >= m) sum += t;
      }
      int excl = sum - ps;
      cnt[2 * tid] = excl;
      cnt[2 * tid + 1] = excl + s0;
      soff[g * 128 + 2 * tid] = g * 4096 + excl;
      soff[g * 128 + 2 * tid + 1] = g * 4096 + excl + s0;
    }
    if (g == 0 && tid == 511) soff[NNODE] = NEDGE;
    __syncthreads();
    UN<8>([&](auto k){
      const int e = g * 4096 + k.v * 512 + tid;
      int slot = atomicAdd(&cnt[dl[k.v]], 1);
      sortedA[g * 4096 + slot] = make_uint4((uint)(e >> 5), gy[k.v], gz[k.v], 0u);
    });
  }
}

// ---------------------------------------------------------------------------
// k_mega: r11's best shape (block = 8 nodes, 256 threads, half-wave per dst)
// + geo precompute + ZERO GLOBAL ATOMICS: group partials are combined in LDS
// and written non-atomically to part[blk][32] (scal@0, mid@16).
// ---------------------------------------------------------------------------
__global__ void __launch_bounds__(256, 3) k_mega(
    const int* __restrict__ soff, const uint4* __restrict__ sortedA,
    const uint4* __restrict__ edgeC,
    const uint* __restrict__ tabU, const float* __restrict__ h,
    const float* __restrict__ sc1,
    const float* __restrict__ l2a0, const float* __restrict__ l2a1,
    const float* __restrict__ l2a2, const float* __restrict__ l2a3,
    const float* __restrict__ l1b0, const float* __restrict__ l1b1,
    const float* __restrict__ l1b2, const float* __restrict__ l1b3,
    float* __restrict__ part)
{
  __shared__ float Atile[8][44];
  __shared__ float nodeHs[8][36];
  __shared__ float scalL[8][10];
  __shared__ float midW[4][16];

  const int tid = threadIdx.x;
  const int lane = tid & 63;
  const int li = lane & 31;
  const int hw = tid >> 5;                       // half-wave id 0..7
  const int dst = blockIdx.x * 8 + hw;

  // ---- Phase A: gather + accumulate + half-wave tree reduce ----
  {
    const int start = soff[dst];
    const int n = soff[dst + 1] - start;

    float acc[42];
    UN<42>([&](auto c){ acc[c.v] = 0.f; });

    const int nmax = max(n, __shfl_xor(n, 32));
#pragma unroll 1
    for (int it = 0; it < nmax; it += 32) {
      const int i = it + li;
      if (i < n) {
        uint4 gg = sortedA[start + i];
        const int src = (int)gg.x;
        float x = __half2float(__ushort_as_half((unsigned short)(gg.y & 0xffffu)));
        float y = __half2float(__ushort_as_half((unsigned short)(gg.y >> 16)));
        float z = __half2float(__ushort_as_half((unsigned short)(gg.z & 0xffffu)));
        const int ti = (int)(gg.z >> 16);
        const uint4* w4 = (const uint4*)(tabU + (size_t)ti * 64);
        uint4 wr[13];
        UN<13>([&](auto j){ wr[j.v] = w4[j.v]; });
        const float4* hp = (const float4*)(h + src * 28);
        float4 hq[7];
        UN<7>([&](auto j){ hq[j.v] = hp[j.v]; });
        float sh[16];
        make_sh_n(x, y, z, sh);

        UN<25>([&](auto mm){
          float t = f4get<mm.v>(hq) * upk<mm.v>(wr);
          UN<16>([&](auto v){ acc[v.v] = fmaf(t, l2a0[mm.v * 16 + v.v], acc[v.v]); });
        });
        {
          float p1[3] = {0.f, 0.f, 0.f};
          UN<25>([&](auto mm){
            float t = f4get<mm.v>(hq) * upk<25 + mm.v>(wr);
            UN<3>([&](auto v){ p1[v.v] = fmaf(t, l2a1[mm.v * 3 + v.v], p1[v.v]); });
          });
          UN<3>([&](auto v){
            UN<3>([&](auto m){ acc[16 + v.v * 3 + m.v] = fmaf(p1[v.v], sh[1 + m.v], acc[16 + v.v * 3 + m.v]); });
          });
        }
        {
          float p2[2] = {0.f, 0.f};
          UN<25>([&](auto mm){
            float t = f4get<mm.v>(hq) * upk<50 + mm.v>(wr);
            UN<2>([&](auto v){ p2[v.v] = fmaf(t, l2a2[mm.v * 2 + v.v], p2[v.v]); });
          });
          UN<2>([&](auto v){
            UN<5>([&](auto m){ acc[25 + v.v * 5 + m.v] = fmaf(p2[v.v], sh[4 + m.v], acc[25 + v.v * 5 + m.v]); });
          });
        }
        {
          float p3 = 0.f;
          UN<25>([&](auto mm){
            float t = f4get<mm.v>(hq) * upk<75 + mm.v>(wr);
            p3 = fmaf(t, l2a3[mm.v], p3);
          });
          UN<7>([&](auto m){ acc[35 + m.v] = fmaf(p3, sh[9 + m.v], acc[35 + m.v]); });
        }
      }
    }

    float red[64];
    UN<42>([&](auto c){ red[c.v] = acc[c.v]; });
    UN<22>([&](auto c){ red[42 + c.v] = 0.f; });
    cred32_rec<0>(red, lane);
    Atile[hw][li] = red[0];
    if (li < 10) Atile[hw][32 + li] = red[1];
  }
  __syncthreads();

  // ---- Phase B: node2 for the block's 8 nodes (8 threads) ----
  if (tid < 8) {
    const int i = blockIdx.x * 8 + tid;
    float Ai[42];
    UN<42>([&](auto c){ Ai[c.v] = Atile[tid][c.v]; });
    const float CS_ = 0.38268343236509f, CX_ = 0.92387953251129f;
    float scal[10], gate[6];
    UN<10>([&](auto c){
      float s = CS_ * sc1[i * 16 + c.v] + CX_ * Ai[c.v];
      scal[c.v] = s * sigmoidf_(s);
      scalL[tid][c.v] = scal[c.v];
    });
    UN<6>([&](auto c){
      float s = CS_ * sc1[i * 16 + 10 + c.v] + CX_ * Ai[10 + c.v];
      gate[c.v] = sigmoidf_(s);
    });
    UN<10>([&](auto v){
      float a = 0.f;
      UN<10>([&](auto u){ a = fmaf(scal[u.v], l1b0[u.v * 10 + v.v], a); });
      nodeHs[tid][v.v] = a * 0.31622776601684f;
    });
    UN<3>([&](auto v){
      UN<3>([&](auto m){
        float a = 0.f;
        UN<3>([&](auto u){ a = fmaf(Ai[16 + u.v * 3 + m.v] * gate[u.v], l1b1[u.v * 3 + v.v], a); });
        nodeHs[tid][10 + v.v * 3 + m.v] = a * 0.57735026918963f;
      });
    });
    UN<2>([&](auto v){
      UN<5>([&](auto m){
        float a = 0.f;
        UN<2>([&](auto u){ a = fmaf(Ai[25 + u.v * 5 + m.v] * gate[3 + u.v], l1b2[u.v * 2 + v.v], a); });
        nodeHs[tid][19 + v.v * 5 + m.v] = a * 0.70710678118655f;
      });
    });
    float b3 = l1b3[0];
    UN<7>([&](auto m){ nodeHs[tid][29 + m.v] = Ai[35 + m.v] * gate[5] * b3; });
  }
  __syncthreads();

  // scal partial: block-sum over 8 nodes -> part[blk][0..9] (non-atomic)
  if (tid < 10) {
    float a = 0.f;
    UN<8>([&](auto u){ a += scalL[u.v][tid]; });
    part[(size_t)blockIdx.x * 32 + tid] = a;
  }

  // ---- Phase C: edge2 for edges e in [blk*256, blk*256+256) ----
  {
    const int e = blockIdx.x * 256 + tid;
    const int sl = tid >> 5;                    // local src index 0..7
    uint4 gg = edgeC[e];
    float x = __half2float(__ushort_as_half((unsigned short)(gg.y & 0xffffu)));
    float y = __half2float(__ushort_as_half((unsigned short)(gg.y >> 16)));
    float z = __half2float(__ushort_as_half((unsigned short)(gg.z & 0xffffu)));
    const int ti = (int)(gg.z >> 16);
    const uint4* w4 = (const uint4*)(tabU + (size_t)ti * 64 + 52);
    uint4 wr[2];
    wr[0] = w4[0]; wr[1] = w4[1];
    float acc[16];
    UN<16>([&](auto c){ acc[c.v] = upk<c.v>(wr); });

    float sh[16];
    make_sh_n(x, y, z, sh);

    const float* Hs = nodeHs[sl];
    float ev[16];
    UN<10>([&](auto c){ ev[c.v] = Hs[c.v] * acc[c.v]; });
    UN<3>([&](auto u){
      float d = 0.f;
      UN<3>([&](auto m){ d = fmaf(Hs[10 + u.v * 3 + m.v], sh[1 + m.v], d); });
      ev[10 + u.v] = d * 0.57735026918963f * acc[10 + u.v];
    });
    UN<2>([&](auto u){
      float d = 0.f;
      UN<5>([&](auto m){ d = fmaf(Hs[19 + u.v * 5 + m.v], sh[4 + m.v], d); });
      ev[13 + u.v] = d * 0.44721359549996f * acc[13 + u.v];
    });
    {
      float d = 0.f;
      UN<7>([&](auto m){ d = fmaf(Hs[29 + m.v], sh[9 + m.v], d); });
      ev[15] = d * 0.37796447300923f * acc[15];
    }

    float s = creduce<16>(ev, lane);
    const int wv = tid >> 6;
    if (lane < 16) midW[wv][lane] = s;
  }
  __syncthreads();
  // mid partial: sum 4 wave slots -> part[blk][16..31] (non-atomic)
  if (tid < 16) {
    float a = (midW[0][tid] + midW[1][tid]) + (midW[2][tid] + midW[3][tid]);
    part[(size_t)blockIdx.x * 32 + 16 + tid] = a;
  }
}

// ---------------------------------------------------------------------------
// k_final (1 block, 1024 threads): reduce 1024 block-partials -> group sums,
// fold head through sc2_w / lin2b, emit 64 outputs.
// Group of block blk: (blk >> 4) & 31  (blocks 0..511 wt, 512..1023 mt).
// ---------------------------------------------------------------------------
__global__ void __launch_bounds__(1024, 1) k_final(
    const float* __restrict__ sc2w, const float* __restrict__ lin2b,
    const float* __restrict__ headw, const float* __restrict__ headb,
    const float* __restrict__ part, float* __restrict__ out)
{
  __shared__ float SS[32][10];
  __shared__ float MM[32][16];
  __shared__ float WA[20];
  __shared__ float WB[32];
  const int t = threadIdx.x;

  if (t < 832) {
    // job: group g, channel c (0..9 scal, 10..25 mid)
    const int g = t / 26, c = t % 26;
    const int off = (c < 10) ? c : (6 + c);     // mid channel c-10 at slot 16+(c-10)
    float a = 0.f;
    UN<16>([&](auto k){
      a += part[(size_t)(g * 16 + k.v) * 32 + off];         // wt half
      a += part[(size_t)(512 + g * 16 + k.v) * 32 + off];   // mt half
    });
    if (c < 10) SS[g][c] = a; else MM[g][c - 10] = a;
  } else if (t < 852) {
    const int q = t - 832, j = q >> 1, o = q & 1;
    float a = 0.f;
    for (int c = 0; c < 256; ++c) a += sc2w[j * 256 + c] * headw[c * 2 + o];
    WA[q] = a;
  } else if (t < 884) {
    const int q = t - 852, j = q >> 1, o = q & 1;
    float a = 0.f;
    for (int c = 0; c < 256; ++c) a += lin2b[j * 256 + c] * headw[c * 2 + o];
    WB[q] = a;
  }
  __syncthreads();

  if (t < 64) {
    const int g = t & 31, o = t >> 5;
    float a = 0.f;
    UN<10>([&](auto j){ a = fmaf(SS[g][j.v], WA[j.v * 2 + o], a); });
    float b = 0.f;
    UN<16>([&](auto j){ b = fmaf(MM[g][j.v], WB[j.v * 2 + o], b); });
    float y = a * (0.38268343236509f * 0.31622776601684f)   // CS * 1/sqrt(10)
            + b * (0.92387953251129f * 0.25f);              // CX * 1/4
    out[o * 32 + g] = y * (1.0f / 256.0f) + headb[o];
  }
}

extern "C" void kernel_launch(void* const* d_in, const int* in_sizes, int n_in,
                              void* d_out, int out_size, void* d_ws, size_t ws_size,
                              hipStream_t stream)
{
  float* ws = (float*)d_ws;
  const float* wt_pos = (const float*)d_in[0];
  const float* mt_pos = (const float*)d_in[1];
  const float* wt_x   = (const float*)d_in[2];
  const float* mt_x   = (const float*)d_in[3];
  const int* edst     = (const int*)d_in[7];
  const float* sc1w   = (const float*)d_in[8];
  const float* lin1a  = (const float*)d_in[9];
  const float* fc1w1  = (const float*)d_in[10];
  const float* fc1w2  = (const float*)d_in[11];
  const float* l2a0   = (const float*)d_in[12];
  const float* l2a1   = (const float*)d_in[13];
  const float* l2a2   = (const float*)d_in[14];
  const float* l2a3   = (const float*)d_in[15];
  const float* sc2w   = (const float*)d_in[16];
  const float* l1b0   = (const float*)d_in[17];
  const float* l1b1   = (const float*)d_in[18];
  const float* l1b2   = (const float*)d_in[19];
  const float* l1b3   = (const float*)d_in[20];
  const float* fc2w1  = (const float*)d_in[21];
  const float* fc2w2  = (const float*)d_in[22];
  const float* lin2b  = (const float*)d_in[23];
  const float* headw  = (const float*)d_in[24];
  const float* headb  = (const float*)d_in[25];

  float* h       = ws + OFF_H;
  float* sc1     = ws + OFF_SC1;
  float* part    = ws + OFF_PART;
  uint*  tabU    = (uint*)(ws + OFF_TABU);
  int*   soff    = (int*)(ws + OFF_SOFF);
  uint4* edgeC   = (uint4*)(ws + OFF_EC);
  uint4* sortedA = (uint4*)(ws + OFF_SA);

  k_prep<<<1104, 512, 0, stream>>>(wt_pos, mt_pos, wt_x, mt_x, lin1a, sc1w,
                                   fc1w1, fc1w2, fc2w1, fc2w2, edst,
                                   h, sc1, tabU, edgeC, sortedA, soff);
  k_mega<<<1024, 256, 0, stream>>>(soff, sortedA, edgeC, tabU, h, sc1,
                                   l2a0, l2a1, l2a2, l2a3,
                                   l1b0, l1b1, l1b2, l1b3, part);
  k_final<<<1, 1024, 0, stream>>>(sc2w, lin2b, headw, headb, part, (float*)d_out);
}

// Round 16
// 58.370 us; speedup vs baseline: 1.6875x; 1.1218x over previous
//
#include <hip/hip_runtime.h>
#include <hip/hip_fp16.h>

typedef unsigned int uint;

#define NH_   4096
#define NNODE 8192
#define NEDGE 262144
#define TS    1024
#define RT    17.4f
#define RIDX  (((float)(TS - 1)) / RT)

// ---- workspace layout (float offsets) ----
#define OFF_H      0        // 8192*28
#define OFF_SC1    229376   // 8192*16
#define OFF_PART   360448   // 1024 blocks * 32 floats (scal[10] @0, mid[16] @16)
#define OFF_TABU   393216   // 1024*64 uints (bf16-packed r-table, scales folded)
#define OFF_SOFF   458752   // 8256 ints (CSR offsets by dst)
#define OFF_EC     467008   // 262144 uint4 (edge-order: dst, geo)
#define OFF_SA     1515584  // 262144 uint4 (dst-sorted: src, geo)

// ---- compile-time unroll ----
template <int I> struct ic { static constexpr int v = I; };
template <int N, typename F>
__device__ __forceinline__ void UN(F&& f) {
  if constexpr (N > 0) { UN<N - 1>(f); f(ic<N - 1>{}); }
}

template <int K>
__device__ __forceinline__ float f4c(float4 v) {
  if constexpr (K == 0) return v.x;
  else if constexpr (K == 1) return v.y;
  else if constexpr (K == 2) return v.z;
  else return v.w;
}
template <int C>
__device__ __forceinline__ float f4get(const float4* v) {
  return f4c<C & 3>(v[C >> 2]);
}
template <int K>
__device__ __forceinline__ uint u4c(uint4 v) {
  if constexpr (K == 0) return v.x;
  else if constexpr (K == 1) return v.y;
  else if constexpr (K == 2) return v.z;
  else return v.w;
}
// unpack bf16-pair channel CH from packed uint4 regs
template <int CH>
__device__ __forceinline__ float upk(const uint4* wr) {
  constexpr int pr = CH >> 1;
  uint u = u4c<pr & 3>(wr[pr >> 2]);
  if constexpr (CH & 1) return __uint_as_float(u & 0xffff0000u);
  else return __uint_as_float(u << 16);
}

__device__ __forceinline__ float sigmoidf_(float v) { return 1.0f / (1.0f + __expf(-v)); }

// full-wave compacting reduction: C channels -> channel (lane & (C-1))
template <int C, int B>
__device__ __forceinline__ void cred_rec(float* a, int lane) {
  if constexpr ((1 << B) < C) {
    const bool hi = (lane >> B) & 1;
    constexpr int n = C >> (B + 1);
    UN<n>([&](auto j){
      float s0 = a[2 * j.v], s1 = a[2 * j.v + 1];
      float send = hi ? s0 : s1;
      float recv = __shfl_xor(send, 1 << B);
      a[j.v] = (hi ? s1 : s0) + recv;
    });
    cred_rec<C, B + 1>(a, lane);
  }
}
template <int C>
__device__ __forceinline__ float creduce(float* v, int lane) {
  cred_rec<C, 0>(v, lane);
  float s = v[0];
#pragma unroll
  for (int m = C; m < 64; m <<= 1) s += __shfl_xor(s, m);
  return s;
}
// half-wave (32-lane) compacting reduction of 64 channels, 5 steps.
template <int B>
__device__ __forceinline__ void cred32_rec(float* a, int lane) {
  if constexpr (B < 5) {
    const bool hi = (lane >> B) & 1;
    constexpr int n = 64 >> (B + 1);
    UN<n>([&](auto j){
      float s0 = a[2 * j.v], s1 = a[2 * j.v + 1];
      float send = hi ? s0 : s1;
      float recv = __shfl_xor(send, 1 << B);
      a[j.v] = (hi ? s1 : s0) + recv;
    });
    cred32_rec<B + 1>(a, lane);
  }
}

__device__ __forceinline__ void make_emb(float r, float* embs) {
  float rb = r * 0.45f;
  UN<10>([&](auto b){ float d = rb - (float)b.v; embs[b.v] = __expf(-d * d); });
}

// sh from pre-normalized direction
__device__ __forceinline__ void make_sh_n(float x, float y, float z, float* sh) {
  float x2 = x * x, y2 = y * y, z2 = z * z;
  float shA = 3.87298334620742f * x * z;
  float shB = 1.93649167310371f * (z2 - x2);
  sh[0] = 1.f;
  sh[1] = 1.73205080756888f * x;
  sh[2] = 1.73205080756888f * y;
  sh[3] = 1.73205080756888f * z;
  sh[4] = shA;
  sh[5] = 3.87298334620742f * x * y;
  sh[6] = 2.23606797749979f * (y2 - 0.5f * (x2 + z2));
  sh[7] = 3.87298334620742f * y * z;
  sh[8] = shB;
  sh[9]  = 1.08012344973464f * (shA * z + shB * x);
  sh[10] = 2.64575131106459f * shA * y;
  sh[11] = 1.62018517460197f * (4.f * y2 - x2 - z2) * x;
  sh[12] = 1.32287565553230f * y * (2.f * y2 - 3.f * x2 - 3.f * z2);
  sh[13] = 1.62018517460197f * z * (4.f * y2 - x2 - z2);
  sh[14] = 2.64575131106459f * shB * y;
  sh[15] = 1.08012344973464f * (shB * z - shA * x);
}

// ---------------------------------------------------------------------------
// k_prep (512-thread blocks, block-ranged):
//   [0,256): r-table build (TS=1024), 4 samples/block (lane = channel).
//   [256,272): node1 (h pad 28, sc1).
//   [272,336): counting sort by dst + per-edge geometry precompute.
// ---------------------------------------------------------------------------
__global__ void __launch_bounds__(512, 2) k_prep(
    const float* __restrict__ wt_pos, const float* __restrict__ mt_pos,
    const float* __restrict__ wt_x, const float* __restrict__ mt_x,
    const float* __restrict__ lin1a, const float* __restrict__ sc1w,
    const float* __restrict__ fc1w1, const float* __restrict__ fc1w2,
    const float* __restrict__ fc2w1, const float* __restrict__ fc2w2,
    const int* __restrict__ edst,
    float* __restrict__ h, float* __restrict__ sc1,
    uint* __restrict__ tabU,
    uint4* __restrict__ edgeC, uint4* __restrict__ sortedA,
    int* __restrict__ soff)
{
  __shared__ float smemf[1024];
  const int blk = blockIdx.x;
  const int tid = threadIdx.x;

  if (blk < 256) {
    // ---- r-table: 4 samples/block, 8 waves (2 per sample) ----
    float (*sv)[2][128] = (float(*)[2][128])smemf;
    const int lane = tid & 63;
    const int wv = tid >> 6;
    const int si = wv >> 1;           // sample 0..3
    const int role = wv & 1;
    const int s = blk * 4 + si;
    const float r = (float)s * (RT / (float)(TS - 1));
    float emb[10];
    make_emb(r, emb);
    const float FS1 = 0.003125f;
    const float FS2 = 0.015625f;

    const float* wmat = (role == 0) ? fc1w1 : fc2w1;
    UN<2>([&](auto hh){
      int kk = lane + hh.v * 64;
      float hk = 0.f;
      UN<10>([&](auto j){ hk = fmaf(emb[j.v], wmat[j.v * 128 + kk], hk); });
      sv[si][role][kk] = hk * sigmoidf_(hk);
    });
    __syncthreads();

    float acc = 0.f;
    if (role == 0) {
      const float* base = fc1w2 + lane;
#pragma unroll 4
      for (int k = 0; k < 128; ++k)
        acc = fmaf(sv[si][0][k], base[k * 100], acc);
      acc *= FS1;
    } else {
      const bool isW1 = lane < 36;
      const bool isW2 = (lane >= 36) && (lane < 52);
      if (isW1 || isW2) {
        const float* base = isW1 ? (fc1w2 + 64 + lane) : (fc2w2 + (lane - 36));
        const int stride = isW1 ? 100 : 16;
        const int svi = isW1 ? 0 : 1;
#pragma unroll 4
        for (int k = 0; k < 128; ++k)
          acc = fmaf(sv[si][svi][k], base[k * stride], acc);
        acc *= (isW1 ? FS1 : FS2);
      }
    }

    int srcLo = 0, srcHi = 0;
    bool valid = false;
    if (role == 0) {
      srcLo = 2 * lane; srcHi = srcLo + 1; valid = lane < 32;
    } else {
      if (lane >= 32 && lane < 50)      { int i = lane - 32; srcLo = 2 * i;      srcHi = 2 * i + 1;  valid = true; }
      else if (lane >= 52 && lane < 60) { int i = lane - 52; srcLo = 36 + 2 * i; srcHi = 37 + 2 * i; valid = true; }
    }
    float lo = __shfl(acc, srcLo);
    float hi = __shfl(acc, srcHi);
    if (valid) {
      uint u = ((__float_as_uint(lo) + 0x8000u) >> 16)
             | (((__float_as_uint(hi) + 0x8000u) >> 16) << 16);
      tabU[(size_t)s * 64 + lane] = u;
    }
  } else if (blk < 272) {
    // ---- node1 ----
    int i = (blk - 256) * 512 + tid;
    const float* xp = (i < NH_) ? (wt_x + i * 25) : (mt_x + (i - NH_) * 25);
    float xr[25];
    UN<25>([&](auto m){ xr[m.v] = xp[m.v]; });
    float ah[25], as[16];
    UN<25>([&](auto j){ ah[j.v] = 0.f; });
    UN<16>([&](auto j){ as[j.v] = 0.f; });
    UN<25>([&](auto m){
      float xm = xr[m.v];
      UN<25>([&](auto j){ ah[j.v] = fmaf(xm, lin1a[m.v * 25 + j.v], ah[j.v]); });
      UN<16>([&](auto j){ as[j.v] = fmaf(xm, sc1w[m.v * 16 + j.v], as[j.v]); });
    });
    UN<25>([&](auto j){ h[i * 28 + j.v] = 0.2f * ah[j.v]; });
    UN<16>([&](auto j){ sc1[i * 16 + j.v] = 0.2f * as[j.v]; });
  } else {
    // ---- sort + geometry: one block per group (4096 edges, 8/thread) ----
    int* hist = (int*)smemf;
    int* cnt  = hist + 128;
    const int g = blk - 272;
    if (tid < 128) hist[tid] = 0;
    __syncthreads();
    int dl[8]; uint gy[8], gz[8];
    UN<8>([&](auto k){
      const int e = g * 4096 + k.v * 512 + tid;
      const int src = e >> 5;
      const int dst = edst[e];
      dl[k.v] = dst & 127;
      atomicAdd(&hist[dl[k.v]], 1);
      const float* ps = (src < NH_) ? (wt_pos + src * 3) : (mt_pos + (src - NH_) * 3);
      const float* pd = (dst < NH_) ? (wt_pos + dst * 3) : (mt_pos + (dst - NH_) * 3);
      float vx = ps[0] - pd[0], vy = ps[1] - pd[1], vz = ps[2] - pd[2];
      float r = sqrtf(vx * vx + vy * vy + vz * vz);
      int ti = min((int)(r * RIDX + 0.5f), TS - 1);
      float rinv = 1.0f / fmaxf(r, 1e-9f);
      uint hx = (uint)__half_as_ushort(__float2half(vx * rinv));
      uint hy = (uint)__half_as_ushort(__float2half(vy * rinv));
      uint hz = (uint)__half_as_ushort(__float2half(vz * rinv));
      gy[k.v] = hx | (hy << 16);
      gz[k.v] = hz | ((uint)ti << 16);
      edgeC[e] = make_uint4((uint)dst, gy[k.v], gz[k.v], 0u);
    });
    __syncthreads();
    if (tid < 64) {
      int s0 = hist[2 * tid], s1 = hist[2 * tid + 1];
      int ps = s0 + s1;
      int sum = ps;
#pragma unroll
      for (int m = 1; m < 64; m <<= 1) {
        int t = __shfl_up(sum, m);
        if (tid >= m) sum += t;
      }
      int excl = sum - ps;
      cnt[2 * tid] = excl;
      cnt[2 * tid + 1] = excl + s0;
      soff[g * 128 + 2 * tid] = g * 4096 + excl;
      soff[g * 128 + 2 * tid + 1] = g * 4096 + excl + s0;
    }
    if (g == 0 && tid == 511) soff[NNODE] = NEDGE;
    __syncthreads();
    UN<8>([&](auto k){
      const int e = g * 4096 + k.v * 512 + tid;
      int slot = atomicAdd(&cnt[dl[k.v]], 1);
      sortedA[g * 4096 + slot] = make_uint4((uint)(e >> 5), gy[k.v], gz[k.v], 0u);
    });
  }
}

// ---------------------------------------------------------------------------
// k_mega: r15 shape (block = 8 nodes, 256 threads, half-wave per dst, zero
// global atomics) + DEFERRED chunk-0 projection: phase A accumulates the raw
// 25 chunk-0 channels (25 FMA/edge instead of 425); the 25x16 l2a0 projection
// is applied once per node in phase B. acc channels: 25 + 9 + 10 + 7 = 51.
// ---------------------------------------------------------------------------
__global__ void __launch_bounds__(256, 3) k_mega(
    const int* __restrict__ soff, const uint4* __restrict__ sortedA,
    const uint4* __restrict__ edgeC,
    const uint* __restrict__ tabU, const float* __restrict__ h,
    const float* __restrict__ sc1,
    const float* __restrict__ l2a0, const float* __restrict__ l2a1,
    const float* __restrict__ l2a2, const float* __restrict__ l2a3,
    const float* __restrict__ l1b0, const float* __restrict__ l1b1,
    const float* __restrict__ l1b2, const float* __restrict__ l1b3,
    float* __restrict__ part)
{
  __shared__ float Atile[8][52];    // raw 51 reduced channels per dst
  __shared__ float nodeHs[8][36];
  __shared__ float scalL[8][10];
  __shared__ float midW[4][16];

  const int tid = threadIdx.x;
  const int lane = tid & 63;
  const int li = lane & 31;
  const int hw = tid >> 5;                       // half-wave id 0..7
  const int dst = blockIdx.x * 8 + hw;

  // ---- Phase A: gather + raw accumulate + half-wave tree reduce ----
  {
    const int start = soff[dst];
    const int n = soff[dst + 1] - start;

    float acc[51];
    UN<51>([&](auto c){ acc[c.v] = 0.f; });

    const int nmax = max(n, __shfl_xor(n, 32));
#pragma unroll 1
    for (int it = 0; it < nmax; it += 32) {
      const int i = it + li;
      if (i < n) {
        uint4 gg = sortedA[start + i];
        const int src = (int)gg.x;
        float x = __half2float(__ushort_as_half((unsigned short)(gg.y & 0xffffu)));
        float y = __half2float(__ushort_as_half((unsigned short)(gg.y >> 16)));
        float z = __half2float(__ushort_as_half((unsigned short)(gg.z & 0xffffu)));
        const int ti = (int)(gg.z >> 16);
        const uint4* w4 = (const uint4*)(tabU + (size_t)ti * 64);
        uint4 wr[13];
        UN<13>([&](auto j){ wr[j.v] = w4[j.v]; });
        const float4* hp = (const float4*)(h + src * 28);
        float4 hq[7];
        UN<7>([&](auto j){ hq[j.v] = hp[j.v]; });
        float sh[16];
        make_sh_n(x, y, z, sh);

        // chunk 0: raw accumulate (projection deferred to phase B)
        UN<25>([&](auto mm){
          acc[mm.v] = fmaf(f4get<mm.v>(hq), upk<mm.v>(wr), acc[mm.v]);
        });
        // chunk 1 -> p1[3] -> acc[25 + v*3 + m'] += p1[v]*sh[1+m']
        {
          float p1[3] = {0.f, 0.f, 0.f};
          UN<25>([&](auto mm){
            float t = f4get<mm.v>(hq) * upk<25 + mm.v>(wr);
            UN<3>([&](auto v){ p1[v.v] = fmaf(t, l2a1[mm.v * 3 + v.v], p1[v.v]); });
          });
          UN<3>([&](auto v){
            UN<3>([&](auto m){ acc[25 + v.v * 3 + m.v] = fmaf(p1[v.v], sh[1 + m.v], acc[25 + v.v * 3 + m.v]); });
          });
        }
        // chunk 2 -> p2[2] -> acc[34 + v*5 + m'] += p2[v]*sh[4+m']
        {
          float p2[2] = {0.f, 0.f};
          UN<25>([&](auto mm){
            float t = f4get<mm.v>(hq) * upk<50 + mm.v>(wr);
            UN<2>([&](auto v){ p2[v.v] = fmaf(t, l2a2[mm.v * 2 + v.v], p2[v.v]); });
          });
          UN<2>([&](auto v){
            UN<5>([&](auto m){ acc[34 + v.v * 5 + m.v] = fmaf(p2[v.v], sh[4 + m.v], acc[34 + v.v * 5 + m.v]); });
          });
        }
        // chunk 3 -> p3 -> acc[44 + m'] += p3*sh[9+m']
        {
          float p3 = 0.f;
          UN<25>([&](auto mm){
            float t = f4get<mm.v>(hq) * upk<75 + mm.v>(wr);
            p3 = fmaf(t, l2a3[mm.v], p3);
          });
          UN<7>([&](auto m){ acc[44 + m.v] = fmaf(p3, sh[9 + m.v], acc[44 + m.v]); });
        }
      }
    }

    float red[64];
    UN<51>([&](auto c){ red[c.v] = acc[c.v]; });
    UN<13>([&](auto c){ red[51 + c.v] = 0.f; });
    cred32_rec<0>(red, lane);
    Atile[hw][li] = red[0];
    if (li < 19) Atile[hw][32 + li] = red[1];
  }
  __syncthreads();

  // ---- Phase B: node2 for the block's 8 nodes (8 threads) ----
  if (tid < 8) {
    const int i = blockIdx.x * 8 + tid;
    float raw[51];
    UN<51>([&](auto c){ raw[c.v] = Atile[tid][c.v]; });
    float Ai[42];
    UN<16>([&](auto v){
      float a = 0.f;
      UN<25>([&](auto m){ a = fmaf(raw[m.v], l2a0[m.v * 16 + v.v], a); });
      Ai[v.v] = a;
    });
    UN<9>([&](auto q){ Ai[16 + q.v] = raw[25 + q.v]; });
    UN<10>([&](auto q){ Ai[25 + q.v] = raw[34 + q.v]; });
    UN<7>([&](auto q){ Ai[35 + q.v] = raw[44 + q.v]; });

    const float CS_ = 0.38268343236509f, CX_ = 0.92387953251129f;
    float scal[10], gate[6];
    UN<10>([&](auto c){
      float s = CS_ * sc1[i * 16 + c.v] + CX_ * Ai[c.v];
      scal[c.v] = s * sigmoidf_(s);
      scalL[tid][c.v] = scal[c.v];
    });
    UN<6>([&](auto c){
      float s = CS_ * sc1[i * 16 + 10 + c.v] + CX_ * Ai[10 + c.v];
      gate[c.v] = sigmoidf_(s);
    });
    UN<10>([&](auto v){
      float a = 0.f;
      UN<10>([&](auto u){ a = fmaf(scal[u.v], l1b0[u.v * 10 + v.v], a); });
      nodeHs[tid][v.v] = a * 0.31622776601684f;
    });
    UN<3>([&](auto v){
      UN<3>([&](auto m){
        float a = 0.f;
        UN<3>([&](auto u){ a = fmaf(Ai[16 + u.v * 3 + m.v] * gate[u.v], l1b1[u.v * 3 + v.v], a); });
        nodeHs[tid][10 + v.v * 3 + m.v] = a * 0.57735026918963f;
      });
    });
    UN<2>([&](auto v){
      UN<5>([&](auto m){
        float a = 0.f;
        UN<2>([&](auto u){ a = fmaf(Ai[25 + u.v * 5 + m.v] * gate[3 + u.v], l1b2[u.v * 2 + v.v], a); });
        nodeHs[tid][19 + v.v * 5 + m.v] = a * 0.70710678118655f;
      });
    });
    float b3 = l1b3[0];
    UN<7>([&](auto m){ nodeHs[tid][29 + m.v] = Ai[35 + m.v] * gate[5] * b3; });
  }
  __syncthreads();

  // scal partial: block-sum over 8 nodes -> part[blk][0..9] (non-atomic)
  if (tid < 10) {
    float a = 0.f;
    UN<8>([&](auto u){ a += scalL[u.v][tid]; });
    part[(size_t)blockIdx.x * 32 + tid] = a;
  }

  // ---- Phase C: edge2 for edges e in [blk*256, blk*256+256) ----
  {
    const int e = blockIdx.x * 256 + tid;
    const int sl = tid >> 5;                    // local src index 0..7
    uint4 gg = edgeC[e];
    float x = __half2float(__ushort_as_half((unsigned short)(gg.y & 0xffffu)));
    float y = __half2float(__ushort_as_half((unsigned short)(gg.y >> 16)));
    float z = __half2float(__ushort_as_half((unsigned short)(gg.z & 0xffffu)));
    const int ti = (int)(gg.z >> 16);
    const uint4* w4 = (const uint4*)(tabU + (size_t)ti * 64 + 52);
    uint4 wr[2];
    wr[0] = w4[0]; wr[1] = w4[1];
    float acc[16];
    UN<16>([&](auto c){ acc[c.v] = upk<c.v>(wr); });

    float sh[16];
    make_sh_n(x, y, z, sh);

    const float* Hs = nodeHs[sl];
    float ev[16];
    UN<10>([&](auto c){ ev[c.v] = Hs[c.v] * acc[c.v]; });
    UN<3>([&](auto u){
      float d = 0.f;
      UN<3>([&](auto m){ d = fmaf(Hs[10 + u.v * 3 + m.v], sh[1 + m.v], d); });
      ev[10 + u.v] = d * 0.57735026918963f * acc[10 + u.v];
    });
    UN<2>([&](auto u){
      float d = 0.f;
      UN<5>([&](auto m){ d = fmaf(Hs[19 + u.v * 5 + m.v], sh[4 + m.v], d); });
      ev[13 + u.v] = d * 0.44721359549996f * acc[13 + u.v];
    });
    {
      float d = 0.f;
      UN<7>([&](auto m){ d = fmaf(Hs[29 + m.v], sh[9 + m.v], d); });
      ev[15] = d * 0.37796447300923f * acc[15];
    }

    float s = creduce<16>(ev, lane);
    const int wv = tid >> 6;
    if (lane < 16) midW[wv][lane] = s;
  }
  __syncthreads();
  // mid partial: sum 4 wave slots -> part[blk][16..31] (non-atomic)
  if (tid < 16) {
    float a = (midW[0][tid] + midW[1][tid]) + (midW[2][tid] + midW[3][tid]);
    part[(size_t)blockIdx.x * 32 + 16 + tid] = a;
  }
}

// ---------------------------------------------------------------------------
// k_final (1 block, 1024 threads): reduce 1024 block-partials -> group sums,
// fold head through sc2_w / lin2b, emit 64 outputs.
// ---------------------------------------------------------------------------
__global__ void __launch_bounds__(1024, 1) k_final(
    const float* __restrict__ sc2w, const float* __restrict__ lin2b,
    const float* __restrict__ headw, const float* __restrict__ headb,
    const float* __restrict__ part, float* __restrict__ out)
{
  __shared__ float SS[32][10];
  __shared__ float MM[32][16];
  __shared__ float WA[20];
  __shared__ float WB[32];
  const int t = threadIdx.x;

  if (t < 832) {
    const int g = t / 26, c = t % 26;
    const int off = (c < 10) ? c : (6 + c);
    float a = 0.f;
    UN<16>([&](auto k){
      a += part[(size_t)(g * 16 + k.v) * 32 + off];         // wt half
      a += part[(size_t)(512 + g * 16 + k.v) * 32 + off];   // mt half
    });
    if (c < 10) SS[g][c] = a; else MM[g][c - 10] = a;
  } else if (t < 852) {
    const int q = t - 832, j = q >> 1, o = q & 1;
    float a = 0.f;
    for (int c = 0; c < 256; ++c) a += sc2w[j * 256 + c] * headw[c * 2 + o];
    WA[q] = a;
  } else if (t < 884) {
    const int q = t - 852, j = q >> 1, o = q & 1;
    float a = 0.f;
    for (int c = 0; c < 256; ++c) a += lin2b[j * 256 + c] * headw[c * 2 + o];
    WB[q] = a;
  }
  __syncthreads();

  if (t < 64) {
    const int g = t & 31, o = t >> 5;
    float a = 0.f;
    UN<10>([&](auto j){ a = fmaf(SS[g][j.v], WA[j.v * 2 + o], a); });
    float b = 0.f;
    UN<16>([&](auto j){ b = fmaf(MM[g][j.v], WB[j.v * 2 + o], b); });
    float y = a * (0.38268343236509f * 0.31622776601684f)   // CS * 1/sqrt(10)
            + b * (0.92387953251129f * 0.25f);              // CX * 1/4
    out[o * 32 + g] = y * (1.0f / 256.0f) + headb[o];
  }
}

extern "C" void kernel_launch(void* const* d_in, const int* in_sizes, int n_in,
                              void* d_out, int out_size, void* d_ws, size_t ws_size,
                              hipStream_t stream)
{
  float* ws = (float*)d_ws;
  const float* wt_pos = (const float*)d_in[0];
  const float* mt_pos = (const float*)d_in[1];
  const float* wt_x   = (const float*)d_in[2];
  const float* mt_x   = (const float*)d_in[3];
  const int* edst     = (const int*)d_in[7];
  const float* sc1w   = (const float*)d_in[8];
  const float* lin1a  = (const float*)d_in[9];
  const float* fc1w1  = (const float*)d_in[10];
  const float* fc1w2  = (const float*)d_in[11];
  const float* l2a0   = (const float*)d_in[12];
  const float* l2a1   = (const float*)d_in[13];
  const float* l2a2   = (const float*)d_in[14];
  const float* l2a3   = (const float*)d_in[15];
  const float* sc2w   = (const float*)d_in[16];
  const float* l1b0   = (const float*)d_in[17];
  const float* l1b1   = (const float*)d_in[18];
  const float* l1b2   = (const float*)d_in[19];
  const float* l1b3   = (const float*)d_in[20];
  const float* fc2w1  = (const float*)d_in[21];
  const float* fc2w2  = (const float*)d_in[22];
  const float* lin2b  = (const float*)d_in[23];
  const float* headw  = (const float*)d_in[24];
  const float* headb  = (const float*)d_in[25];

  float* h       = ws + OFF_H;
  float* sc1     = ws + OFF_SC1;
  float* part    = ws + OFF_PART;
  uint*  tabU    = (uint*)(ws + OFF_TABU);
  int*   soff    = (int*)(ws + OFF_SOFF);
  uint4* edgeC   = (uint4*)(ws + OFF_EC);
  uint4* sortedA = (uint4*)(ws + OFF_SA);

  k_prep<<<336, 512, 0, stream>>>(wt_pos, mt_pos, wt_x, mt_x, lin1a, sc1w,
                                  fc1w1, fc1w2, fc2w1, fc2w2, edst,
                                  h, sc1, tabU, edgeC, sortedA, soff);
  k_mega<<<1024, 256, 0, stream>>>(soff, sortedA, edgeC, tabU, h, sc1,
                                   l2a0, l2a1, l2a2, l2a3,
                                   l1b0, l1b1, l1b2, l1b3, part);
  k_final<<<1, 1024, 0, stream>>>(sc2w, lin2b, headw, headb, part, (float*)d_out);
}